// Round 2
// baseline (112.838 us; speedup 1.0000x reference)
//
#include <hip/hip_runtime.h>

#define IN_CH 128
#define NHC   64   // HEADS*OUT_CH
#define OUT_C 16

// ws layout: [0, 4*n_nodes) flags ints; at byte 1<<20: mode int
// mode = 1 -> edge_index buffer is int32, col at words [E, 2E)
// mode = 0 -> edge_index buffer is int64, col low words at 2E + 2e

// flags[i] = 0 for all nodes; block 0 additionally probes the edge-index layout.
__global__ void init_kernel(const int* __restrict__ ei, int* __restrict__ flags,
                            int* __restrict__ mode, int n_nodes) {
    int i = blockIdx.x * blockDim.x + threadIdx.x;
    if (i < n_nodes) flags[i] = 0;
    if (blockIdx.x == 0) {
        __shared__ int s_mode;
        if (threadIdx.x == 0) s_mode = 0;
        __syncthreads();
        // Odd int32 words of first 512: int64 layout -> high halves of values
        // < 2^31 -> all zero. int32 layout -> random node ids, ~surely nonzero.
        int v = ei[2 * threadIdx.x + 1];
        if (v != 0) atomicOr(&s_mode, 1);
        __syncthreads();
        if (threadIdx.x == 0) *mode = s_mode;
    }
}

// flags[col[e]] = 1 (racy same-value stores fine)
__global__ void flag_kernel(const int* __restrict__ ei, const int* __restrict__ mode,
                            int* __restrict__ flags, int E, int n_nodes) {
    int e = blockIdx.x * blockDim.x + threadIdx.x;
    if (e >= E) return;
    int m = *mode;  // wave-uniform scalar load
    int c = m ? ei[E + e]           // int32 layout
              : ei[2 * E + 2 * e];  // int64 layout: low word of col[e]
    if ((unsigned)c < (unsigned)n_nodes) flags[c] = 1;
}

// out[n,c] = flag[n] * dot(x[n,:], Wm[:,c]),  Wm[k,c] = 0.25*sum_h W[k,h*16+c]
// 256 threads -> 64 nodes/block; lane q = tid&3 owns channels [4q, 4q+4).
__global__ __launch_bounds__(256) void out_kernel(
    const float* __restrict__ x,     // fp32 [N,128]
    const float* __restrict__ W,     // fp32 [128,64]
    const int* __restrict__ flags,
    float* __restrict__ out,         // fp32 [N,16]
    int n_nodes)
{
    __shared__ alignas(16) float wlds[IN_CH * OUT_C];  // 8 KB
    const int tid = threadIdx.x;

    for (int i = tid; i < IN_CH * OUT_C; i += 256) {
        int k = i >> 4, c = i & 15;
        const float* wr = W + k * NHC + c;
        wlds[i] = 0.25f * (wr[0] + wr[16] + wr[32] + wr[48]);
    }
    __syncthreads();

    const int g = tid >> 2;          // node sub-index 0..63
    const int q = tid & 3;           // channel quad
    const int node = blockIdx.x * 64 + g;
    const int nclamp = min(node, n_nodes - 1);

    const float4* x4 = (const float4*)x;
    const float4* w4 = (const float4*)wlds;
    const size_t xb = (size_t)nclamp * (IN_CH / 4);

    float4 acc = make_float4(0.f, 0.f, 0.f, 0.f);

    #pragma unroll 8
    for (int kk = 0; kk < IN_CH / 4; ++kk) {
        // 4 lanes per node share the address -> wave fetches 16 distinct 16B rows chunks
        float4 xv = x4[xb + kk];
        float xf[4] = {xv.x, xv.y, xv.z, xv.w};
        #pragma unroll
        for (int i = 0; i < 4; ++i) {
            // 4 distinct LDS addresses/wave, 16-way same-address broadcast
            float4 w = w4[(kk * 4 + i) * 4 + q];
            acc.x += xf[i] * w.x;
            acc.y += xf[i] * w.y;
            acc.z += xf[i] * w.z;
            acc.w += xf[i] * w.w;
        }
    }

    if (node < n_nodes) {
        float fs = flags[node] ? 1.0f : 0.0f;
        float4 o = make_float4(acc.x * fs, acc.y * fs, acc.z * fs, acc.w * fs);
        // float4 index node*4+q: consecutive across the wave -> 1KB coalesced store
        ((float4*)out)[(size_t)node * 4 + q] = o;
    }
}

extern "C" void kernel_launch(void* const* d_in, const int* in_sizes, int n_in,
                              void* d_out, int out_size, void* d_ws, size_t ws_size,
                              hipStream_t stream) {
    const float* x        = (const float*)d_in[0];  // fp32 [N,128]
    const int*   ei       = (const int*)d_in[1];    // int32 or int64 [2,E] (probed)
    const float* W        = (const float*)d_in[2];  // fp32 [128,64]
    // d_in[3] (att) is mathematically irrelevant: segment-softmax weights sum
    // to 1 and multiply the segment-constant vector x_proj[col].

    const int E       = in_sizes[1] / 2;
    const int n_nodes = in_sizes[0] / IN_CH;

    int* flags = (int*)d_ws;
    int* mode  = (int*)((char*)d_ws + (1 << 20));

    init_kernel<<<dim3((n_nodes + 255) / 256), dim3(256), 0, stream>>>(ei, flags, mode, n_nodes);
    flag_kernel<<<dim3((E + 255) / 256), dim3(256), 0, stream>>>(ei, mode, flags, E, n_nodes);
    out_kernel<<<dim3((n_nodes + 63) / 64), dim3(256), 0, stream>>>(
        x, W, flags, (float*)d_out, n_nodes);
}